// Round 3
// baseline (139.769 us; speedup 1.0000x reference)
//
#include <hip/hip_runtime.h>
#include <stdint.h>
#include <stddef.h>

// ---- problem constants ----
#define K_CODES 1024
#define D_DIM   256
#define HW      1024      // 32*32 spatial
#define N_VEC   32768
#define TOT_ELEMS 8388608
#define NBLK    512       // vq_main grid

typedef float    v4f __attribute__((ext_vector_type(4)));
typedef _Float16 v8h __attribute__((ext_vector_type(8)));

// async global->LDS, 16B/lane, dest = wave-uniform base + lane*16
__device__ __forceinline__ void gld_lds16(const void* g, void* l) {
    __builtin_amdgcn_global_load_lds(
        (const __attribute__((address_space(1))) void*)g,
        (__attribute__((address_space(3))) void*)l, 16, 0, 0);
}

// ------------------------------------------------------------------
// K1: codebook -> fp16 copy + 0.5*||e||^2  (+ zero loss_acc & counter,
// replacing the hipMemsetAsync graph node). Numerics identical to the
// previous version.
__global__ void prep_emb(const float* __restrict__ emb,
                         _Float16* __restrict__ emb_h,
                         float* __restrict__ hnorm,
                         float* __restrict__ loss_acc,
                         unsigned* __restrict__ cnt) {
    int k = blockIdx.x, t = threadIdx.x;
    if (k == 0 && t == 0) { loss_acc[0] = 0.f; cnt[0] = 0u; }
    float v = emb[(size_t)k * D_DIM + t];
    emb_h[(size_t)k * D_DIM + t] = (_Float16)v;
    float s = v * v;
    for (int off = 32; off; off >>= 1) s += __shfl_down(s, off);
    __shared__ float wsum[4];
    if ((t & 63) == 0) wsum[t >> 6] = s;
    __syncthreads();
    if (t == 0) hnorm[k] = 0.5f * (wsum[0] + wsum[1] + wsum[2] + wsum[3]);
}

// ------------------------------------------------------------------
// K2: fully fused VQ. 512 blocks x 512 thr (8 waves), 64 rows/block.
// 2 blocks/CU resident (LDS ~70 KB, VGPR<=128 via launch_bounds) so
// barrier drains / scattered-load latency overlap across blocks.
// Intra-block K-split x2: waves 0-3 scan codes 0-511, waves 4-7 codes
// 512-1023, same 64 rows; LDS merge. dist' = 0.5||e||^2 - <z,e>.
// Codebook tiles: 32 codes (16 KB), double-buffered per K-half.
// Swizzle: granule g of code k stored at slot u = g ^ (k&7)
//   -> read bank-group = (g&7)^(col&7): 8 groups x2 per quarter (free).
// Finalize folded in via last-block-done ticket (cnt zeroed by K1).
__global__ __launch_bounds__(512, 4) void
vq_main(const float* __restrict__ z,
        const _Float16* __restrict__ emb_h,
        const float* __restrict__ emb,
        const float* __restrict__ hnorm,
        float* __restrict__ out,
        float* __restrict__ loss_acc,
        unsigned* __restrict__ cnt) {
    // btile: [2 grp][2 buf][16 KB] = 64 KB; epilogue zq overlays
    // (32 rows x 257 floats = 32896 B <= 65536 B).
    __shared__ __align__(16) char smem[65536];
    __shared__ float  norm_s[K_CODES];
    __shared__ int    idx_s[64];
    __shared__ float2 mrg[4][16];
    __shared__ float  wred[8];

    _Float16* btile = (_Float16*)smem;

    int t    = threadIdx.x;
    int wave = t >> 6;
    int lane = t & 63;
    int grp  = wave >> 2;     // K-half
    int wv   = wave & 3;      // row-tile selector (16 rows each)
    int col  = lane & 15;
    int quad = lane >> 4;
    int b    = blockIdx.x >> 4;
    int hw0  = (blockIdx.x & 15) * 64;
    const float* zb = z + (size_t)b * D_DIM * HW;

    // stage tile T (32 codes, 16 KB) of this wave's K-half
    auto stage = [&](int buf, int T) {
        const char* src = (const char*)emb_h
                          + (size_t)(grp * 512 + T * 32) * 512;
        char* dst = (char*)smem + (grp * 2 + buf) * 16384 + wv * 4096;
#pragma unroll
        for (int i = 0; i < 4; ++i) {
            int kloc = wv * 8 + i * 2 + (lane >> 5);
            int g    = (lane & 31) ^ (kloc & 7);
            gld_lds16(src + (size_t)kloc * 512 + (size_t)g * 16,
                      dst + i * 1024);
        }
    };
    stage(0, 0);

    for (int i = t; i < K_CODES; i += 512) norm_s[i] = hnorm[i];

    // A fragments: 16 rows/wave (both K-halves load the same rows)
    int m0 = hw0 + wv * 16;
    v8h af[8];
#pragma unroll
    for (int c = 0; c < 8; ++c) {
#pragma unroll
        for (int j = 0; j < 8; ++j) {
            int d = c * 32 + quad * 8 + j;
            af[c][j] = (_Float16)zb[(size_t)d * HW + m0 + col];
        }
    }

    float minv[4]; int mini[4];
#pragma unroll
    for (int r = 0; r < 4; ++r) { minv[r] = 3.4e38f; mini[r] = 0; }

    for (int T = 0; T < 16; ++T) {
        __syncthreads();                 // staged buffer ready
        if (T < 15) stage((T + 1) & 1, T + 1);
        const _Float16* bt = btile + (size_t)(grp * 2 + (T & 1)) * 8192;
#pragma unroll
        for (int cc = 0; cc < 2; ++cc) {
            int k = cc * 16 + col;
            v8h bf[8];
#pragma unroll
            for (int c = 0; c < 8; ++c) {
                int u = (c * 4 + quad) ^ (col & 7);   // k&7 == col&7
                bf[c] = *(const v8h*)(bt + (size_t)k * D_DIM + (u << 3));
            }
            v4f acc = {0.f, 0.f, 0.f, 0.f};
#pragma unroll
            for (int c = 0; c < 8; ++c)
                acc = __builtin_amdgcn_mfma_f32_16x16x32_f16(af[c], bf[c], acc, 0, 0, 0);
            int   code = grp * 512 + T * 32 + k;
            float n    = norm_s[code];
#pragma unroll
            for (int r = 0; r < 4; ++r) {
                float d0 = n - acc[r];
                if (d0 < minv[r]) { minv[r] = d0; mini[r] = code; }
            }
        }
    }
    // reduce across the 16 cols of each quad
#pragma unroll
    for (int off = 1; off < 16; off <<= 1) {
#pragma unroll
        for (int r = 0; r < 4; ++r) {
            float ov = __shfl_xor(minv[r], off);
            int   oi = __shfl_xor(mini[r], off);
            if (ov < minv[r] || (ov == minv[r] && oi < mini[r])) {
                minv[r] = ov; mini[r] = oi;
            }
        }
    }
    // K-split merge: half-1 posts, half-0 merges (strict < keeps low idx)
    if (grp == 1 && col == 0) {
#pragma unroll
        for (int r = 0; r < 4; ++r)
            mrg[wv][quad * 4 + r] = make_float2(minv[r], __int_as_float(mini[r]));
    }
    __syncthreads();
    if (grp == 0 && col == 0) {
#pragma unroll
        for (int r = 0; r < 4; ++r) {
            int rl = quad * 4 + r;
            float2 m2 = mrg[wv][rl];
            int mi = mini[r];
            if (m2.x < minv[r]) mi = __float_as_int(m2.y);
            idx_s[wv * 16 + rl] = mi;
        }
    }
    __syncthreads();

    // ---- epilogue: gather emb rows -> LDS, write out + fused loss ----
    // 64 rows in two 32-row passes; all 8 waves cooperate.
    float* zq = (float*)smem;                 // 32 x 257 floats
    int tt = t & 255, th = t >> 8;            // th in {0,1}
    float sum = 0.f;
    for (int s = 0; s < 2; ++s) {
        if (s) __syncthreads();
#pragma unroll
        for (int ii = 0; ii < 16; ++ii) {
            int i = th * 16 + ii;
            zq[i * 257 + tt] =
                emb[(size_t)idx_s[s * 32 + i] * D_DIM + tt];
        }
        __syncthreads();
        int j = t & 31, dblk = t >> 5;        // dblk 0..15
#pragma unroll
        for (int p = 0; p < 16; ++p) {
            int d = dblk * 16 + p;
            size_t o = (size_t)(b * D_DIM + d) * HW
                       + hw0 + s * 32 + j;
            float q  = zq[j * 257 + d];
            float e  = z[o];
            float df = q - e;
            sum += df * df;
            out[o] = q;                 // z_q_st == z_q numerically
        }
    }
    for (int off = 32; off; off >>= 1) sum += __shfl_down(sum, off);
    if (lane == 0) wred[wave] = sum;
    __syncthreads();
    if (t == 0) {
        float s8 = 0.f;
#pragma unroll
        for (int i = 0; i < 8; ++i) s8 += wred[i];
        atomicAdd(loss_acc, s8);
        __threadfence();
        if (atomicAdd(cnt, 1u) == NBLK - 1) {
            // all blocks' loss adds are visible at the L2 atomic point
            float total = atomicAdd(loss_acc, 0.0f);
            out[TOT_ELEMS] = total * (1.25f / (float)TOT_ELEMS);
        }
    }
}

// ------------------------------------------------------------------
extern "C" void kernel_launch(void* const* d_in, const int* in_sizes, int n_in,
                              void* d_out, int out_size, void* d_ws, size_t ws_size,
                              hipStream_t stream) {
    const float* z   = (const float*)d_in[0];   // [32,256,32,32]
    const float* emb = (const float*)d_in[1];   // [1024,256]
    float* out = (float*)d_out;                 // [8388608 z_q_st][1 loss]

    char* ws = (char*)d_ws;
    float*    loss_acc = (float*)ws;            // @0
    unsigned* cnt      = (unsigned*)(ws + 4);   // last-block ticket
    float*    hnorm    = (float*)(ws + 1024);   // 4 KB
    _Float16* emb_h    = (_Float16*)(ws + 8192);// 512 KB

    prep_emb<<<dim3(K_CODES), dim3(256), 0, stream>>>(emb, emb_h, hnorm,
                                                      loss_acc, cnt);
    vq_main<<<dim3(NBLK), dim3(512), 0, stream>>>(z, emb_h, emb, hnorm,
                                                  out, loss_acc, cnt);
}